// Round 11
// baseline (111.456 us; speedup 1.0000x reference)
//
#include <hip/hip_runtime.h>
#include <hip/hip_bf16.h>
#include <cstdint>
#include <cstddef>

#define BB 2
#define SS 2048
#define DD 1024
#define HH 16
#define EE 64

typedef short bf16x8 __attribute__((ext_vector_type(8)));
typedef short s4 __attribute__((ext_vector_type(4)));
typedef float f32x4 __attribute__((ext_vector_type(4)));
typedef float float4v __attribute__((ext_vector_type(4)));
typedef unsigned int u32x2 __attribute__((ext_vector_type(2)));

#define GLDS(gp, lp) __builtin_amdgcn_global_load_lds( \
    (const __attribute__((address_space(1))) void*)(gp), \
    (__attribute__((address_space(3))) void*)(lp), 16, 0, 0)

static __device__ __forceinline__ short f2bf(float f) {
    union { float f; uint32_t u; } v; v.f = f;
    uint32_t r = (v.u + 0x7fffu + ((v.u >> 16) & 1u)) >> 16;
    return (short)r;
}

// packed f32x2 -> bf16x2 (RNE), single HW op
static __device__ __forceinline__ uint32_t cvtpk(float a, float b) {
    uint32_t r;
    asm("v_cvt_pk_bf16_f32 %0, %1, %2" : "=v"(r) : "v"(a), "v"(b));
    return r;
}

// ------------- fused prep: x convert (blocks 0..4095), W transposes (4096..4879) -------------
__global__ __launch_bounds__(256) void prep_kernel(const float* __restrict__ x,
                                                   const float* __restrict__ Wq,
                                                   const float* __restrict__ Wk,
                                                   const float* __restrict__ Wv,
                                                   const float* __restrict__ W,
                                                   short* __restrict__ xb,
                                                   short* __restrict__ wt,
                                                   short* __restrict__ wot) {
    __shared__ float tile[64][65];
    int blk = blockIdx.x;
    int t = threadIdx.x;
    if (blk < 4096) {
        int i = blk * 256 + t;      // n4 = 1048576 = 4096*256 exactly
        float4v v = ((const float4v*)x)[i];
        s4 o; o[0] = f2bf(v[0]); o[1] = f2bf(v[1]); o[2] = f2bf(v[2]); o[3] = f2bf(v[3]);
        ((s4*)xb)[i] = o;
        return;
    }
    int idx = blk - 4096;
    const float* src;
    short* d;
    int R, r0;
    if (idx < 768) {
        int bx = idx & 15, by = idx >> 4;
        int which = by >> 4, mtx = by & 15;
        src = ((which == 0) ? Wq : (which == 1) ? Wk : Wv) + (size_t)mtx * DD * 64;
        d = wt + (size_t)which * HH * EE * DD + (size_t)mtx * DD * 64;
        R = DD; r0 = bx * 64;
    } else {
        int bx = idx - 768;
        src = W; d = wot; R = HH * EE; r0 = bx * 64;
    }
#pragma unroll
    for (int i = 0; i < 16; ++i) {
        int id2 = t + i * 256;
        int r = id2 >> 6, c = id2 & 63;
        tile[r][c] = src[(size_t)(r0 + r) * 64 + c];
    }
    __syncthreads();
#pragma unroll
    for (int i = 0; i < 16; ++i) {
        int id2 = t + i * 256;
        int e = id2 >> 6, dd2 = id2 & 63;
        d[(size_t)e * R + r0 + dd2] = f2bf(tile[dd2][e]);
    }
}

// ------------- QKV GEMM: 256x256 tile, BK=32, 8 waves, triple-buffer, counted vmcnt -------------
__global__ __launch_bounds__(512, 2) void qkv_gemm(const short* __restrict__ A,
                                                   const short* __restrict__ Bt,
                                                   short* __restrict__ Qo,
                                                   short* __restrict__ Ko,
                                                   short* __restrict__ Vto) {
    __shared__ __align__(16) short As3[3][128 * 64];
    __shared__ __align__(16) short Bs3[3][128 * 64];
    int tid = threadIdx.x;
    int wv = tid >> 6, lane = tid & 63;
    int m = lane & 15, g = lane >> 4;
    int wr = wv >> 2, wc = wv & 3;

    int xcd = blockIdx.x & 7, idx = blockIdx.x >> 3;
    int mb = (xcd & 3) * 4 + (idx & 3);
    int nb = (xcd >> 2) * 6 + (idx >> 2);
    int rowBase = mb * 256, colBase0 = nb * 256;

    int src_row[2], src_kcol[2];
#pragma unroll
    for (int j = 0; j < 2; ++j) {
        int si = j * 512 + tid;
        int sr = si >> 3, sp = si & 7;
        int sl = sp ^ (sr & 7);
        src_row[j] = 2 * sr + (sl >> 2);
        src_kcol[j] = (sl & 3) * 8;
    }
    const short* aP0 = A + (size_t)(rowBase + src_row[0]) * DD + src_kcol[0];
    const short* aP1 = A + (size_t)(rowBase + src_row[1]) * DD + src_kcol[1];
    const short* bP0 = Bt + (size_t)(colBase0 + src_row[0]) * DD + src_kcol[0];
    const short* bP1 = Bt + (size_t)(colBase0 + src_row[1]) * DD + src_kcol[1];
    int dst0 = (wv * 64) * 8;
    int dst1 = (512 + wv * 64) * 8;

    f32x4 acc[8][4];
#pragma unroll
    for (int i = 0; i < 8; ++i)
#pragma unroll
        for (int j = 0; j < 4; ++j) acc[i][j] = {0, 0, 0, 0};

    int rdoff = ((m & 1) * 64 + g * 16) ^ (((m >> 1) & 7) << 4);
    int mh = m >> 1;

    auto STAGE = [&](int buf, int kt) {
        short* ab = &As3[buf][0];
        short* bb = &Bs3[buf][0];
        GLDS(aP0 + kt, ab + dst0);
        GLDS(aP1 + kt, ab + dst1);
        GLDS(bP0 + kt, bb + dst0);
        GLDS(bP1 + kt, bb + dst1);
    };

    auto COMPUTE = [&](int buf) {
        bf16x8 af[8], bfr[4];
#pragma unroll
        for (int mi = 0; mi < 8; ++mi)
            af[mi] = *(const bf16x8*)((const char*)&As3[buf][(wr * 64 + mi * 8 + mh) * 64] + rdoff);
#pragma unroll
        for (int ni = 0; ni < 4; ++ni)
            bfr[ni] = *(const bf16x8*)((const char*)&Bs3[buf][(wc * 32 + ni * 8 + mh) * 64] + rdoff);
        asm volatile("s_waitcnt lgkmcnt(0)\ns_barrier" ::: "memory");
        __builtin_amdgcn_s_setprio(1);
#pragma unroll
        for (int mi = 0; mi < 8; ++mi)
#pragma unroll
            for (int ni = 0; ni < 4; ++ni)
                acc[mi][ni] = __builtin_amdgcn_mfma_f32_16x16x32_bf16(af[mi], bfr[ni], acc[mi][ni], 0, 0, 0);
        __builtin_amdgcn_s_setprio(0);
    };

    STAGE(0, 0);
    STAGE(1, 32);
    for (int t = 0; t < 30; ++t) {
        STAGE((t + 2) % 3, (t + 2) * 32);
        asm volatile("s_waitcnt vmcnt(8)\ns_barrier" ::: "memory");
        COMPUTE(t % 3);
    }
    asm volatile("s_waitcnt vmcnt(4)\ns_barrier" ::: "memory");
    COMPUTE(0);
    asm volatile("s_waitcnt vmcnt(0)\ns_barrier" ::: "memory");
    COMPUTE(1);

    int colw = colBase0 + wc * 64;
    int mtx = colw >> 10;
    int h = (colw >> 6) & 15;
    int rb = rowBase + wr * 128;

    if (mtx == 0) {
        const float qs = 0.125f * 1.44269504089f;   // fold 1/sqrt(E) and log2(e)
#pragma unroll
        for (int mi = 0; mi < 8; ++mi)
#pragma unroll
            for (int ni = 0; ni < 4; ++ni)
#pragma unroll
                for (int r = 0; r < 4; ++r) {
                    int row = rb + mi * 16 + g * 4 + r;
                    int b = row >> 11, s = row & 2047;
                    Qo[((size_t)(b * HH + h) * SS + s) * EE + ni * 16 + m] = f2bf(acc[mi][ni][r] * qs);
                }
    } else if (mtx == 1) {
#pragma unroll
        for (int mi = 0; mi < 8; ++mi)
#pragma unroll
            for (int ni = 0; ni < 4; ++ni)
#pragma unroll
                for (int r = 0; r < 4; ++r) {
                    int row = rb + mi * 16 + g * 4 + r;
                    int b = row >> 11, s = row & 2047;
                    Ko[((size_t)(b * HH + h) * SS + s) * EE + ni * 16 + m] = f2bf(acc[mi][ni][r]);
                }
    } else {
#pragma unroll
        for (int mi = 0; mi < 8; ++mi)
#pragma unroll
            for (int ni = 0; ni < 4; ++ni) {
                int row0 = rb + mi * 16 + g * 4;
                int b = row0 >> 11, s = row0 & 2047;
                s4 o; o[0] = f2bf(acc[mi][ni][0]); o[1] = f2bf(acc[mi][ni][1]);
                o[2] = f2bf(acc[mi][ni][2]); o[3] = f2bf(acc[mi][ni][3]);
                *(s4*)&Vto[((size_t)(b * HH + h) * EE + ni * 16 + m) * SS + s] = o;
            }
    }
}

// ------------- flash attention (causal): paired q-blocks + triple-buffer counted vmcnt -------------
// Block = 4 waves; pass A = q-block 31-pair (tiles 0..qblkA), pass B = q-block pair
// (tiles 0..qblkB): 33 uniform tile-slots. K/V triple-buffered, depth-2 prefetch,
// vmcnt(8) in-loop (never 0). No VMEM in loop except staging: both passes' Q
// preloaded; pass-A output parked in VGPRs, written at the end.
__global__ __launch_bounds__(256, 2) void attn_kernel(const short* __restrict__ Q,
                                                      const short* __restrict__ K,
                                                      const short* __restrict__ Vt,
                                                      short* __restrict__ ctx) {
    __shared__ __align__(16) short Ks[3][64 * 64];
    __shared__ __align__(16) short Vs[3][64 * 64];
    __shared__ __align__(16) short pl[4][16][72];
    int tid = threadIdx.x;
    int wv = tid >> 6, lane = tid & 63;
    int m = lane & 15, g = lane >> 4;
    // XCD swizzle: each XCD owns 4 heads x 16 pairs (K/V 2MB <= L2)
    int wg = (blockIdx.x & 7) * 64 + (blockIdx.x >> 3);
    int bh = wg >> 4;
    int pair = wg & 15;
    int qblkA = 31 - pair, qblkB = pair;     // qblkA in [16,31]
    int b = bh >> 4, h = bh & 15;
    const short* Qb = Q + (size_t)bh * SS * EE;
    const short* Kb = K + (size_t)bh * SS * EE;
    const short* Vb = Vt + (size_t)bh * EE * SS;

    int srow = wv * 8 + (lane >> 3);
    int scol_s = (((lane & 7) * 16) ^ ((srow & 7) << 4)) >> 1;

    int sw = (m & 7) << 4;
    int c0 = (g * 16) ^ sw;
    int c1 = (64 + g * 16) ^ sw;

    auto TILEOF = [&](int u) { return u <= qblkA ? u : u - qblkA - 1; };

    auto STAGE = [&](int buf, int tile) {
        int t0 = tile * 64;
        short* kd = &Ks[buf][0] + wv * 512;
        short* vd = &Vs[buf][0] + wv * 512;
        const short* ksrc = Kb + (size_t)(t0 + srow) * EE + scol_s;
        const short* vsrc = Vb + (size_t)srow * SS + t0 + scol_s;
        GLDS(ksrc, kd);
        GLDS(ksrc + 32 * EE, kd + 2048);
        GLDS(vsrc, vd);
        GLDS(vsrc + (size_t)32 * SS, vd + 2048);
    };

    // preload BOTH passes' Q fragments (oldest-first vmcnt drains these under the
    // first vmcnt(8); no VMEM loads inside the loop keeps the ledger exact)
    int qrowA = qblkA * 64 + wv * 16 + m;
    int qrowB = qblkB * 64 + wv * 16 + m;
    bf16x8 qaA0 = *(const bf16x8*)(Qb + (size_t)qrowA * EE + g * 8);
    bf16x8 qaA1 = *(const bf16x8*)(Qb + (size_t)qrowA * EE + 32 + g * 8);
    bf16x8 qaB0 = *(const bf16x8*)(Qb + (size_t)qrowB * EE + g * 8);
    bf16x8 qaB1 = *(const bf16x8*)(Qb + (size_t)qrowB * EE + 32 + g * 8);

    bf16x8 qa0 = qaA0, qa1 = qaA1;
    int qrow = qrowA;
    float mreg = -INFINITY, lsum = 0.f;
    f32x4 o[4];
#pragma unroll
    for (int n = 0; n < 4; ++n) { o[n][0] = 0.f; o[n][1] = 0.f; o[n][2] = 0.f; o[n][3] = 0.f; }
    u32x2 oApk[4];

    STAGE(0, 0);
    STAGE(1, 1);          // TILEOF(1)=1 since qblkA >= 16

    for (int s = 0; s < 33; ++s) {
        if (s <= 30) {
            STAGE((s + 2) % 3, TILEOF(s + 2));
            asm volatile("s_waitcnt vmcnt(8)" ::: "memory");     // oldest 4 = tile s staged
        } else if (s == 31) {
            asm volatile("s_waitcnt vmcnt(4)" ::: "memory");
        } else {
            asm volatile("s_waitcnt vmcnt(0)" ::: "memory");
        }
        asm volatile("s_barrier" ::: "memory");

        int t0 = TILEOF(s) * 64;
        const short* Ksb = &Ks[s % 3][0];
        const short* Vsb = &Vs[s % 3][0];

        // S^T = K x Q (scores in log2 domain via Q pre-scale)
        f32x4 sc[4] = {{0,0,0,0},{0,0,0,0},{0,0,0,0},{0,0,0,0}};
#pragma unroll
        for (int n = 0; n < 4; ++n) {
            const char* krow = (const char*)(Ksb + (n * 16 + m) * 64);
            bf16x8 kb0 = *(const bf16x8*)(krow + c0);
            sc[n] = __builtin_amdgcn_mfma_f32_16x16x32_bf16(kb0, qa0, sc[n], 0, 0, 0);
            bf16x8 kb1 = *(const bf16x8*)(krow + c1);
            sc[n] = __builtin_amdgcn_mfma_f32_16x16x32_bf16(kb1, qa1, sc[n], 0, 0, 0);
        }

        // diagonal tile: s==qblkA (pass A) or s==32 (pass B)
        if (s == qblkA || s == 32) {
#pragma unroll
            for (int n = 0; n < 4; ++n)
#pragma unroll
                for (int r = 0; r < 4; ++r)
                    if (t0 + n * 16 + g * 4 + r > qrow) sc[n][r] = -INFINITY;
        }

        // row max: 15 in-lane fmax + 2 shuffles
        float mx = sc[0][0];
#pragma unroll
        for (int n = 0; n < 4; ++n)
#pragma unroll
            for (int r = 0; r < 4; ++r) mx = fmaxf(mx, sc[n][r]);
        mx = fmaxf(mx, __shfl_xor(mx, 16, 64));
        mx = fmaxf(mx, __shfl_xor(mx, 32, 64));

        // defer-max (11.5 log2-units ~ 8 nats)
        if (!__all(mx <= mreg + 11.5f)) {
            float mn = fmaxf(mreg, mx);
            float al = exp2f(mreg - mn);
            lsum *= al;
#pragma unroll
            for (int n = 0; n < 4; ++n)
#pragma unroll
                for (int r = 0; r < 4; ++r) o[n][r] *= al;
            mreg = mn;
        }

        // exp2 + partial sum + cvt_pk P pack to LDS (wave-private)
#pragma unroll
        for (int n = 0; n < 4; ++n) {
            float p0 = exp2f(sc[n][0] - mreg);
            float p1 = exp2f(sc[n][1] - mreg);
            float p2 = exp2f(sc[n][2] - mreg);
            float p3 = exp2f(sc[n][3] - mreg);
            lsum += (p0 + p1) + (p2 + p3);
            u32x2 pk; pk[0] = cvtpk(p0, p1); pk[1] = cvtpk(p2, p3);
            *(u32x2*)&pl[wv][m][n * 16 + g * 4] = pk;
        }

        // PV: o^T += V^T x P
#pragma unroll
        for (int ks = 0; ks < 2; ++ks) {
            bf16x8 pa = *(const bf16x8*)&pl[wv][m][ks * 32 + g * 8];
            int cv = ks ? c1 : c0;
#pragma unroll
            for (int n = 0; n < 4; ++n) {
                const char* vrow = (const char*)(Vsb + (n * 16 + m) * 64);
                bf16x8 vb = *(const bf16x8*)(vrow + cv);
                o[n] = __builtin_amdgcn_mfma_f32_16x16x32_bf16(vb, pa, o[n], 0, 0, 0);
            }
        }

        // pass switch: finalize A into registers (no stores -> vmcnt ledger intact)
        if (s == qblkA) {
            float ls = lsum;
            ls += __shfl_xor(ls, 16, 64);
            ls += __shfl_xor(ls, 32, 64);
            float inv = 1.0f / ls;
#pragma unroll
            for (int n = 0; n < 4; ++n) {
                oApk[n][0] = cvtpk(o[n][0] * inv, o[n][1] * inv);
                oApk[n][1] = cvtpk(o[n][2] * inv, o[n][3] * inv);
            }
            qa0 = qaB0; qa1 = qaB1; qrow = qrowB;
            mreg = -INFINITY; lsum = 0.f;
#pragma unroll
            for (int n = 0; n < 4; ++n) { o[n][0] = 0.f; o[n][1] = 0.f; o[n][2] = 0.f; o[n][3] = 0.f; }
        }

        // all LDS reads of buf s%3 done before it is re-staged at s+3
        asm volatile("s_waitcnt lgkmcnt(0)\ns_barrier" ::: "memory");
    }

    // write pass A (parked) and pass B outputs
    short* cbA = ctx + (size_t)(b * SS + qrowA) * (HH * EE) + h * EE;
#pragma unroll
    for (int n = 0; n < 4; ++n)
        *(u32x2*)&cbA[n * 16 + g * 4] = oApk[n];

    lsum += __shfl_xor(lsum, 16, 64);
    lsum += __shfl_xor(lsum, 32, 64);
    float inv = 1.0f / lsum;
    short* cbB = ctx + (size_t)(b * SS + qrowB) * (HH * EE) + h * EE;
#pragma unroll
    for (int n = 0; n < 4; ++n) {
        u32x2 k0; k0[0] = cvtpk(o[n][0] * inv, o[n][1] * inv);
        k0[1] = cvtpk(o[n][2] * inv, o[n][3] * inv);
        *(u32x2*)&cbB[n * 16 + g * 4] = k0;
    }
}

// ------------- output projection: ctx [4096,1024] @ W [1024,64] -> out fp32 -------------
__global__ __launch_bounds__(256) void outproj_kernel(const short* __restrict__ ctx,
                                                      const short* __restrict__ wot,
                                                      float* __restrict__ out) {
    __shared__ float red[4][1024];
    int wv = threadIdx.x >> 6, lane = threadIdx.x & 63;
    int m = lane & 15, g = lane >> 4;
    int r0 = blockIdx.x * 16;
    const short* arow = ctx + (size_t)(r0 + m) * (HH * EE) + g * 8;
    const short* wb = wot + g * 8;
    f32x4 acc[4] = {{0,0,0,0},{0,0,0,0},{0,0,0,0},{0,0,0,0}};
    int k0 = wv * 256;
    for (int d0 = k0; d0 < k0 + 256; d0 += 32) {
        bf16x8 a = *(const bf16x8*)(arow + d0);
#pragma unroll
        for (int n = 0; n < 4; ++n) {
            bf16x8 bbf = *(const bf16x8*)(wb + (size_t)(n * 16 + m) * (HH * EE) + d0);
            acc[n] = __builtin_amdgcn_mfma_f32_16x16x32_bf16(a, bbf, acc[n], 0, 0, 0);
        }
    }
#pragma unroll
    for (int n = 0; n < 4; ++n)
#pragma unroll
        for (int r = 0; r < 4; ++r)
            red[wv][(g * 4 + r) * 64 + n * 16 + m] = acc[n][r];
    __syncthreads();
    int t = threadIdx.x;
    float4v sum = ((const float4v*)red[0])[t];
    sum += ((const float4v*)red[1])[t];
    sum += ((const float4v*)red[2])[t];
    sum += ((const float4v*)red[3])[t];
    ((float4v*)(out + (size_t)blockIdx.x * 1024))[t] = sum;
}

extern "C" void kernel_launch(void* const* d_in, const int* in_sizes, int n_in,
                              void* d_out, int out_size, void* d_ws, size_t ws_size,
                              hipStream_t stream) {
    const float* x  = (const float*)d_in[0];
    const float* Wq = (const float*)d_in[1];
    const float* Wk = (const float*)d_in[2];
    const float* Wv = (const float*)d_in[3];
    const float* W  = (const float*)d_in[4];
    float* out = (float*)d_out;

    char* w = (char*)d_ws;
    short* xb  = (short*)w;                                   // 8 MB
    short* wqt = (short*)(w + ((size_t)8 << 20));             // 2 MB each, contiguous = Bt
    short* wot = wqt + (size_t)3 * HH * EE * DD;              // 128 KB
    short* Qb  = wot + (size_t)64 * 1024;                     // 8 MB each
    short* Kb  = Qb + (size_t)BB * HH * SS * EE;
    short* Vtb = Kb + (size_t)BB * HH * SS * EE;
    short* ctx = Vtb + (size_t)BB * HH * SS * EE;             // 8 MB

    prep_kernel<<<4880, 256, 0, stream>>>(x, Wq, Wk, Wv, W, xb, wqt, wot);
    qkv_gemm<<<192, 512, 0, stream>>>(xb, wqt, Qb, Kb, Vtb);
    attn_kernel<<<512, 256, 0, stream>>>(Qb, Kb, Vtb, ctx);
    outproj_kernel<<<256, 256, 0, stream>>>(ctx, wot, out);
}

// Round 12
// 106.387 us; speedup vs baseline: 1.0477x; 1.0477x over previous
//
#include <hip/hip_runtime.h>
#include <hip/hip_bf16.h>
#include <cstdint>
#include <cstddef>

#define BB 2
#define SS 2048
#define DD 1024
#define HH 16
#define EE 64

typedef short bf16x8 __attribute__((ext_vector_type(8)));
typedef short s4 __attribute__((ext_vector_type(4)));
typedef float f32x4 __attribute__((ext_vector_type(4)));
typedef float float4v __attribute__((ext_vector_type(4)));
typedef unsigned int u32x2 __attribute__((ext_vector_type(2)));

#define GLDS(gp, lp) __builtin_amdgcn_global_load_lds( \
    (const __attribute__((address_space(1))) void*)(gp), \
    (__attribute__((address_space(3))) void*)(lp), 16, 0, 0)

static __device__ __forceinline__ short f2bf(float f) {
    union { float f; uint32_t u; } v; v.f = f;
    uint32_t r = (v.u + 0x7fffu + ((v.u >> 16) & 1u)) >> 16;
    return (short)r;
}

// packed f32x2 -> bf16x2 (RNE), single HW op
static __device__ __forceinline__ uint32_t cvtpk(float a, float b) {
    uint32_t r;
    asm("v_cvt_pk_bf16_f32 %0, %1, %2" : "=v"(r) : "v"(a), "v"(b));
    return r;
}

// ------------- fused prep: x convert (blocks 0..4095), W transposes (4096..4879) -------------
__global__ __launch_bounds__(256) void prep_kernel(const float* __restrict__ x,
                                                   const float* __restrict__ Wq,
                                                   const float* __restrict__ Wk,
                                                   const float* __restrict__ Wv,
                                                   const float* __restrict__ W,
                                                   short* __restrict__ xb,
                                                   short* __restrict__ wt,
                                                   short* __restrict__ wot) {
    __shared__ float tile[64][65];
    int blk = blockIdx.x;
    int t = threadIdx.x;
    if (blk < 4096) {
        int i = blk * 256 + t;      // n4 = 1048576 = 4096*256 exactly
        float4v v = ((const float4v*)x)[i];
        s4 o; o[0] = f2bf(v[0]); o[1] = f2bf(v[1]); o[2] = f2bf(v[2]); o[3] = f2bf(v[3]);
        ((s4*)xb)[i] = o;
        return;
    }
    int idx = blk - 4096;
    const float* src;
    short* d;
    int R, r0;
    if (idx < 768) {
        int bx = idx & 15, by = idx >> 4;
        int which = by >> 4, mtx = by & 15;
        src = ((which == 0) ? Wq : (which == 1) ? Wk : Wv) + (size_t)mtx * DD * 64;
        d = wt + (size_t)which * HH * EE * DD + (size_t)mtx * DD * 64;
        R = DD; r0 = bx * 64;
    } else {
        int bx = idx - 768;
        src = W; d = wot; R = HH * EE; r0 = bx * 64;
    }
#pragma unroll
    for (int i = 0; i < 16; ++i) {
        int id2 = t + i * 256;
        int r = id2 >> 6, c = id2 & 63;
        tile[r][c] = src[(size_t)(r0 + r) * 64 + c];
    }
    __syncthreads();
#pragma unroll
    for (int i = 0; i < 16; ++i) {
        int id2 = t + i * 256;
        int e = id2 >> 6, dd2 = id2 & 63;
        d[(size_t)e * R + r0 + dd2] = f2bf(tile[dd2][e]);
    }
}

// ------------- QKV GEMM: 256x256 tile, BK=32, 8 waves, triple-buffer, counted vmcnt -------------
__global__ __launch_bounds__(512, 2) void qkv_gemm(const short* __restrict__ A,
                                                   const short* __restrict__ Bt,
                                                   short* __restrict__ Qo,
                                                   short* __restrict__ Ko,
                                                   short* __restrict__ Vto) {
    __shared__ __align__(16) short As3[3][128 * 64];
    __shared__ __align__(16) short Bs3[3][128 * 64];
    int tid = threadIdx.x;
    int wv = tid >> 6, lane = tid & 63;
    int m = lane & 15, g = lane >> 4;
    int wr = wv >> 2, wc = wv & 3;

    int xcd = blockIdx.x & 7, idx = blockIdx.x >> 3;
    int mb = (xcd & 3) * 4 + (idx & 3);
    int nb = (xcd >> 2) * 6 + (idx >> 2);
    int rowBase = mb * 256, colBase0 = nb * 256;

    int src_row[2], src_kcol[2];
#pragma unroll
    for (int j = 0; j < 2; ++j) {
        int si = j * 512 + tid;
        int sr = si >> 3, sp = si & 7;
        int sl = sp ^ (sr & 7);
        src_row[j] = 2 * sr + (sl >> 2);
        src_kcol[j] = (sl & 3) * 8;
    }
    const short* aP0 = A + (size_t)(rowBase + src_row[0]) * DD + src_kcol[0];
    const short* aP1 = A + (size_t)(rowBase + src_row[1]) * DD + src_kcol[1];
    const short* bP0 = Bt + (size_t)(colBase0 + src_row[0]) * DD + src_kcol[0];
    const short* bP1 = Bt + (size_t)(colBase0 + src_row[1]) * DD + src_kcol[1];
    int dst0 = (wv * 64) * 8;
    int dst1 = (512 + wv * 64) * 8;

    f32x4 acc[8][4];
#pragma unroll
    for (int i = 0; i < 8; ++i)
#pragma unroll
        for (int j = 0; j < 4; ++j) acc[i][j] = {0, 0, 0, 0};

    int rdoff = ((m & 1) * 64 + g * 16) ^ (((m >> 1) & 7) << 4);
    int mh = m >> 1;

    auto STAGE = [&](int buf, int kt) {
        short* ab = &As3[buf][0];
        short* bb = &Bs3[buf][0];
        GLDS(aP0 + kt, ab + dst0);
        GLDS(aP1 + kt, ab + dst1);
        GLDS(bP0 + kt, bb + dst0);
        GLDS(bP1 + kt, bb + dst1);
    };

    auto COMPUTE = [&](int buf) {
        bf16x8 af[8], bfr[4];
#pragma unroll
        for (int mi = 0; mi < 8; ++mi)
            af[mi] = *(const bf16x8*)((const char*)&As3[buf][(wr * 64 + mi * 8 + mh) * 64] + rdoff);
#pragma unroll
        for (int ni = 0; ni < 4; ++ni)
            bfr[ni] = *(const bf16x8*)((const char*)&Bs3[buf][(wc * 32 + ni * 8 + mh) * 64] + rdoff);
        asm volatile("s_waitcnt lgkmcnt(0)\ns_barrier" ::: "memory");
        __builtin_amdgcn_s_setprio(1);
#pragma unroll
        for (int mi = 0; mi < 8; ++mi)
#pragma unroll
            for (int ni = 0; ni < 4; ++ni)
                acc[mi][ni] = __builtin_amdgcn_mfma_f32_16x16x32_bf16(af[mi], bfr[ni], acc[mi][ni], 0, 0, 0);
        __builtin_amdgcn_s_setprio(0);
    };

    STAGE(0, 0);
    STAGE(1, 32);
    for (int t = 0; t < 30; ++t) {
        STAGE((t + 2) % 3, (t + 2) * 32);
        asm volatile("s_waitcnt vmcnt(8)\ns_barrier" ::: "memory");
        COMPUTE(t % 3);
    }
    asm volatile("s_waitcnt vmcnt(4)\ns_barrier" ::: "memory");
    COMPUTE(0);
    asm volatile("s_waitcnt vmcnt(0)\ns_barrier" ::: "memory");
    COMPUTE(1);

    int colw = colBase0 + wc * 64;
    int mtx = colw >> 10;
    int h = (colw >> 6) & 15;
    int rb = rowBase + wr * 128;

    if (mtx == 0) {
        const float qs = 0.125f * 1.44269504089f;   // fold 1/sqrt(E) and log2(e)
#pragma unroll
        for (int mi = 0; mi < 8; ++mi)
#pragma unroll
            for (int ni = 0; ni < 4; ++ni)
#pragma unroll
                for (int r = 0; r < 4; ++r) {
                    int row = rb + mi * 16 + g * 4 + r;
                    int b = row >> 11, s = row & 2047;
                    Qo[((size_t)(b * HH + h) * SS + s) * EE + ni * 16 + m] = f2bf(acc[mi][ni][r] * qs);
                }
    } else if (mtx == 1) {
#pragma unroll
        for (int mi = 0; mi < 8; ++mi)
#pragma unroll
            for (int ni = 0; ni < 4; ++ni)
#pragma unroll
                for (int r = 0; r < 4; ++r) {
                    int row = rb + mi * 16 + g * 4 + r;
                    int b = row >> 11, s = row & 2047;
                    Ko[((size_t)(b * HH + h) * SS + s) * EE + ni * 16 + m] = f2bf(acc[mi][ni][r]);
                }
    } else {
#pragma unroll
        for (int mi = 0; mi < 8; ++mi)
#pragma unroll
            for (int ni = 0; ni < 4; ++ni) {
                int row0 = rb + mi * 16 + g * 4;
                int b = row0 >> 11, s = row0 & 2047;
                s4 o; o[0] = f2bf(acc[mi][ni][0]); o[1] = f2bf(acc[mi][ni][1]);
                o[2] = f2bf(acc[mi][ni][2]); o[3] = f2bf(acc[mi][ni][3]);
                *(s4*)&Vto[((size_t)(b * HH + h) * EE + ni * 16 + m) * SS + s] = o;
            }
    }
}

// ------------- flash attention (causal): r9 structure, 40960B LDS -> 4 blocks/CU -------------
// Block = 4 waves = 64 q-rows of one head; 1024 blocks, heavy-first per XCD,
// XCD owns 4 heads (K/V 2MB <= per-XCD L2). K/V double-buffered LDS (XOR-swizzled
// both sides); P tile swizzled into 64-wide rows (no pad). Swapped QK^T lane-local
// softmax in exp2 domain, cvt_pk P-pack, defer-max 11.5 log2-units.
__global__ __launch_bounds__(256, 4) void attn_kernel(const short* __restrict__ Q,
                                                      const short* __restrict__ K,
                                                      const short* __restrict__ Vt,
                                                      short* __restrict__ ctx) {
    __shared__ __align__(16) short Ks[2][64 * 64];
    __shared__ __align__(16) short Vs[2][64 * 64];
    __shared__ __align__(16) short pl[4][1024];     // per-wave 16x64 P tile, swizzled
    int tid = threadIdx.x;
    int wv = tid >> 6, lane = tid & 63;
    int m = lane & 15, g = lane >> 4;
    // XCD swizzle: xcd = bid&7 owns heads 4*xcd..4*xcd+3; heavy q-blocks first
    int xcd = blockIdx.x & 7, i = blockIdx.x >> 3;  // i in [0,128)
    int bh = xcd * 4 + (i & 3);
    int qblk = 31 - (i >> 2);
    int b = bh >> 4, h = bh & 15;
    const short* Qb = Q + (size_t)bh * SS * EE;
    const short* Kb = K + (size_t)bh * SS * EE;
    const short* Vb = Vt + (size_t)bh * EE * SS;
    int qrow = qblk * 64 + wv * 16 + m;

    int srow = wv * 8 + (lane >> 3);
    int scol_s = (((lane & 7) * 16) ^ ((srow & 7) << 4)) >> 1;

    bf16x8 qa0 = *(const bf16x8*)(Qb + (size_t)qrow * EE + g * 8);
    bf16x8 qa1 = *(const bf16x8*)(Qb + (size_t)qrow * EE + 32 + g * 8);

    int sw = (m & 7) << 4;
    int c0 = (g * 16) ^ sw;
    int c1 = (64 + g * 16) ^ sw;
    char* plrow = (char*)&pl[wv][0] + m * 128;

    float mreg = -INFINITY, lsum = 0.f;
    f32x4 o[4];
#pragma unroll
    for (int n = 0; n < 4; ++n) { o[n][0] = 0.f; o[n][1] = 0.f; o[n][2] = 0.f; o[n][3] = 0.f; }

    auto STAGE = [&](int nb, int t0) {
        short* kd = &Ks[0][0] + nb * 4096 + wv * 512;
        short* vd = &Vs[0][0] + nb * 4096 + wv * 512;
        const short* ksrc = Kb + (size_t)(t0 + srow) * EE + scol_s;
        const short* vsrc = Vb + (size_t)srow * SS + t0 + scol_s;
        GLDS(ksrc, kd);
        GLDS(ksrc + 32 * EE, kd + 2048);
        GLDS(vsrc, vd);
        GLDS(vsrc + (size_t)32 * SS, vd + 2048);
    };

    int ntile = qblk + 1;
    STAGE(0, 0);
    __syncthreads();

    for (int tt = 0; tt < ntile; ++tt) {
        if (tt + 1 < ntile) STAGE((tt + 1) & 1, (tt + 1) * 64);
        int t0 = tt * 64;
        const short* Ksb = &Ks[0][0] + (tt & 1) * 4096;
        const short* Vsb = &Vs[0][0] + (tt & 1) * 4096;

        // S^T = K x Q (scores in log2 domain via Q pre-scale)
        f32x4 sc[4] = {{0,0,0,0},{0,0,0,0},{0,0,0,0},{0,0,0,0}};
#pragma unroll
        for (int n = 0; n < 4; ++n) {
            const char* krow = (const char*)(Ksb + (n * 16 + m) * 64);
            bf16x8 kb0 = *(const bf16x8*)(krow + c0);
            sc[n] = __builtin_amdgcn_mfma_f32_16x16x32_bf16(kb0, qa0, sc[n], 0, 0, 0);
            bf16x8 kb1 = *(const bf16x8*)(krow + c1);
            sc[n] = __builtin_amdgcn_mfma_f32_16x16x32_bf16(kb1, qa1, sc[n], 0, 0, 0);
        }

        if (tt == qblk) {
#pragma unroll
            for (int n = 0; n < 4; ++n)
#pragma unroll
                for (int r = 0; r < 4; ++r)
                    if (t0 + n * 16 + g * 4 + r > qrow) sc[n][r] = -INFINITY;
        }

        // row max: 15 in-lane fmax + 2 shuffles
        float mx = sc[0][0];
#pragma unroll
        for (int n = 0; n < 4; ++n)
#pragma unroll
            for (int r = 0; r < 4; ++r) mx = fmaxf(mx, sc[n][r]);
        mx = fmaxf(mx, __shfl_xor(mx, 16, 64));
        mx = fmaxf(mx, __shfl_xor(mx, 32, 64));

        // defer-max (11.5 log2-units ~ 8 nats)
        if (!__all(mx <= mreg + 11.5f)) {
            float mn = fmaxf(mreg, mx);
            float al = exp2f(mreg - mn);
            lsum *= al;
#pragma unroll
            for (int n = 0; n < 4; ++n)
#pragma unroll
                for (int r = 0; r < 4; ++r) o[n][r] *= al;
            mreg = mn;
        }

        // exp2 + partial sum + cvt_pk P pack to LDS (swizzled row, matches c0/c1 on read)
#pragma unroll
        for (int n = 0; n < 4; ++n) {
            float p0 = exp2f(sc[n][0] - mreg);
            float p1 = exp2f(sc[n][1] - mreg);
            float p2 = exp2f(sc[n][2] - mreg);
            float p3 = exp2f(sc[n][3] - mreg);
            lsum += (p0 + p1) + (p2 + p3);
            u32x2 pk; pk[0] = cvtpk(p0, p1); pk[1] = cvtpk(p2, p3);
            *(u32x2*)(plrow + ((n * 32 + g * 8) ^ sw)) = pk;
        }

        // PV: o^T += V^T x P
#pragma unroll
        for (int ks = 0; ks < 2; ++ks) {
            int cv = ks ? c1 : c0;
            bf16x8 pa = *(const bf16x8*)(plrow + cv);
#pragma unroll
            for (int n = 0; n < 4; ++n) {
                const char* vrow = (const char*)(Vsb + (n * 16 + m) * 64);
                bf16x8 vb = *(const bf16x8*)(vrow + cv);
                o[n] = __builtin_amdgcn_mfma_f32_16x16x32_bf16(vb, pa, o[n], 0, 0, 0);
            }
        }

        __syncthreads();
    }

    lsum += __shfl_xor(lsum, 16, 64);
    lsum += __shfl_xor(lsum, 32, 64);
    float inv = 1.0f / lsum;
    short* cb = ctx + (size_t)(b * SS + qrow) * (HH * EE) + h * EE;
#pragma unroll
    for (int n = 0; n < 4; ++n) {
        u32x2 k0; k0[0] = cvtpk(o[n][0] * inv, o[n][1] * inv);
        k0[1] = cvtpk(o[n][2] * inv, o[n][3] * inv);
        *(u32x2*)&cb[n * 16 + g * 4] = k0;
    }
}

// ------------- output projection: ctx [4096,1024] @ W [1024,64] -> out fp32 -------------
__global__ __launch_bounds__(256) void outproj_kernel(const short* __restrict__ ctx,
                                                      const short* __restrict__ wot,
                                                      float* __restrict__ out) {
    __shared__ float red[4][1024];
    int wv = threadIdx.x >> 6, lane = threadIdx.x & 63;
    int m = lane & 15, g = lane >> 4;
    int r0 = blockIdx.x * 16;
    const short* arow = ctx + (size_t)(r0 + m) * (HH * EE) + g * 8;
    const short* wb = wot + g * 8;
    f32x4 acc[4] = {{0,0,0,0},{0,0,0,0},{0,0,0,0},{0,0,0,0}};
    int k0 = wv * 256;
    for (int d0 = k0; d0 < k0 + 256; d0 += 32) {
        bf16x8 a = *(const bf16x8*)(arow + d0);
#pragma unroll
        for (int n = 0; n < 4; ++n) {
            bf16x8 bbf = *(const bf16x8*)(wb + (size_t)(n * 16 + m) * (HH * EE) + d0);
            acc[n] = __builtin_amdgcn_mfma_f32_16x16x32_bf16(a, bbf, acc[n], 0, 0, 0);
        }
    }
#pragma unroll
    for (int n = 0; n < 4; ++n)
#pragma unroll
        for (int r = 0; r < 4; ++r)
            red[wv][(g * 4 + r) * 64 + n * 16 + m] = acc[n][r];
    __syncthreads();
    int t = threadIdx.x;
    float4v sum = ((const float4v*)red[0])[t];
    sum += ((const float4v*)red[1])[t];
    sum += ((const float4v*)red[2])[t];
    sum += ((const float4v*)red[3])[t];
    ((float4v*)(out + (size_t)blockIdx.x * 1024))[t] = sum;
}

extern "C" void kernel_launch(void* const* d_in, const int* in_sizes, int n_in,
                              void* d_out, int out_size, void* d_ws, size_t ws_size,
                              hipStream_t stream) {
    const float* x  = (const float*)d_in[0];
    const float* Wq = (const float*)d_in[1];
    const float* Wk = (const float*)d_in[2];
    const float* Wv = (const float*)d_in[3];
    const float* W  = (const float*)d_in[4];
    float* out = (float*)d_out;

    char* w = (char*)d_ws;
    short* xb  = (short*)w;                                   // 8 MB
    short* wqt = (short*)(w + ((size_t)8 << 20));             // 2 MB each, contiguous = Bt
    short* wot = wqt + (size_t)3 * HH * EE * DD;              // 128 KB
    short* Qb  = wot + (size_t)64 * 1024;                     // 8 MB each
    short* Kb  = Qb + (size_t)BB * HH * SS * EE;
    short* Vtb = Kb + (size_t)BB * HH * SS * EE;
    short* ctx = Vtb + (size_t)BB * HH * SS * EE;             // 8 MB

    prep_kernel<<<4880, 256, 0, stream>>>(x, Wq, Wk, Wv, W, xb, wqt, wot);
    qkv_gemm<<<192, 512, 0, stream>>>(xb, wqt, Qb, Kb, Vtb);
    attn_kernel<<<1024, 256, 0, stream>>>(Qb, Kb, Vtb, ctx);
    outproj_kernel<<<256, 256, 0, stream>>>(ctx, wot, out);
}